// Round 11
// baseline (822.739 us; speedup 1.0000x reference)
//
#include <hip/hip_runtime.h>
#include <math.h>

#define NB 8
#define N0 16384
#define NC 128
#define NE 98304

typedef unsigned short ushort_t;
using short8 = __attribute__((ext_vector_type(8))) short;
using f32x4 = __attribute__((ext_vector_type(4))) float;

// ---------- helpers ----------
__device__ __forceinline__ unsigned mono_u(float f) {
  unsigned u = __float_as_uint(f);
  return (u & 0x80000000u) ? ~u : (u | 0x80000000u);
}
__device__ __forceinline__ int f2ikey(float f) {
  int i = __float_as_int(f);
  return (i >= 0) ? i : (i ^ 0x7fffffff);
}
__device__ __forceinline__ float ikey2f(int k) {
  return __int_as_float(k >= 0 ? k : (k ^ 0x7fffffff));
}
__device__ __forceinline__ ushort_t f2bf_rne(float f) {
  unsigned u = __float_as_uint(f);
  unsigned r = u + 0x7fffu + ((u >> 16) & 1u);
  return (ushort_t)(r >> 16);
}

// ---------- init: edges copy + depth-0 degree count, readout bufs ----------
// cnt must be pre-zeroed.
__global__ void k_init(const int* __restrict__ src, const int* __restrict__ dst,
                       int* __restrict__ srcw, int* __restrict__ dstw,
                       int* __restrict__ cnt, int* __restrict__ maxbuf, float* __restrict__ sumbuf) {
  int stride = gridDim.x * blockDim.x;
  int i = blockIdx.x * blockDim.x + threadIdx.x;
  for (int j = i; j < NB * NE; j += stride) {
    int d = dst[j];
    srcw[j] = src[j];
    dstw[j] = d;
    atomicAdd(&cnt[(j / NE) * N0 + d], 1);
  }
  for (int j = i; j < 4 * NB * NC; j += stride) {
    maxbuf[j] = (int)0x80000000;
    sumbuf[j] = 0.f;
  }
}

// ---------- weight prep: W[k][c] f32 -> Wt[c][k] bf16 ----------
__global__ void k_wprep(const float* __restrict__ W, ushort_t* __restrict__ Wt) {
  int id = blockIdx.x * blockDim.x + threadIdx.x;
  if (id >= NC * NC) return;
  int k = id >> 7, c = id & 127;
  Wt[c * NC + k] = f2bf_rne(W[id]);
}

// ---------- CSR build: per-graph exclusive scan; zeroes cnt for reuse ----------
__global__ __launch_bounds__(1024) void k_scan(int* __restrict__ cnt,
                                               int* __restrict__ offs, int* __restrict__ cursor) {
  __shared__ int ws[1024];
  int b = blockIdx.x, t = threadIdx.x;
  int base = b * N0 + t * 16;
  int loc[16];
  int s = 0;
#pragma unroll
  for (int j = 0; j < 16; j++) { loc[j] = cnt[base + j]; s += loc[j]; cnt[base + j] = 0; }
  ws[t] = s;
  __syncthreads();
  for (int o = 1; o < 1024; o <<= 1) {
    int v = (t >= o) ? ws[t - o] : 0;
    __syncthreads();
    ws[t] += v;
    __syncthreads();
  }
  int excl = ws[t] - s;
#pragma unroll
  for (int j = 0; j < 16; j++) {
    offs[base + j] = excl;
    cursor[base + j] = excl;
    excl += loc[j];
  }
}

// ---------- CSR build: fill edge list; cursor ends as end-offset ----------
__global__ void k_fill(const int* __restrict__ srcw, const int* __restrict__ dstw,
                       int* __restrict__ cursor, int* __restrict__ elist) {
  int tot = NB * NE;
  for (int i = blockIdx.x * blockDim.x + threadIdx.x; i < tot; i += gridDim.x * blockDim.x) {
    int d = dstw[i];
    if (d < 0) continue;
    int b = i / NE;
    int pos = atomicAdd(&cursor[b * N0 + d], 1);
    elist[b * NE + pos] = srcw[i];
  }
}

// ---------- gather, channel-split with round-9-identical summation order ----------
// Pass computes 64 channels [c0, c0+64): per-graph random working set 4.2 MB -> L2-fit.
// EXACT round-9 chain structure: h = lane>>5 half-waves; acc0 takes edges j+h
// (stride 4), acc1 edges j+2+h; same tail; (acc0+acc1) then shfl_xor(32).
// Only the per-lane payload changed (float2, 64 channels) -> bit-identical h0.
__global__ void k_gather_h(const float* __restrict__ X, ushort_t* __restrict__ H,
                           const int* __restrict__ offs, const int* __restrict__ cend,
                           const int* __restrict__ elist, int n, int c0) {
  int b = blockIdx.x & 7;
  int chunk = blockIdx.x >> 3;
  int lane = threadIdx.x & 63, wid = threadIdx.x >> 6;
  int node = chunk * 4 + wid;
  if (node >= n) return;
  int off = offs[b * N0 + node];
  int deg = cend[b * N0 + node] - off;
  int h = lane >> 5, c2 = lane & 31;
  const float* Xb = X + (size_t)b * N0 * NC + c0;

  float2 acc0 = make_float2(0.f, 0.f);
  float2 acc1 = make_float2(0.f, 0.f);
  if (h == 0) acc0 = *reinterpret_cast<const float2*>(&Xb[(size_t)node * NC + c2 * 2]);

  for (int base = 0; base < deg; base += 64) {
    int m = min(64, deg - base);
    int eid = (lane < m) ? elist[b * NE + off + base + lane] : 0;
    int j = 0;
    for (; j + 4 <= m; j += 4) {
      int s0 = __shfl(eid, j + h);
      int s1 = __shfl(eid, j + 2 + h);
      float2 v0 = *reinterpret_cast<const float2*>(&Xb[(size_t)s0 * NC + c2 * 2]);
      float2 v1 = *reinterpret_cast<const float2*>(&Xb[(size_t)s1 * NC + c2 * 2]);
      acc0.x += v0.x; acc0.y += v0.y;
      acc1.x += v1.x; acc1.y += v1.y;
    }
    if (j + 2 <= m) {
      int s0 = __shfl(eid, j + h);
      float2 v0 = *reinterpret_cast<const float2*>(&Xb[(size_t)s0 * NC + c2 * 2]);
      acc0.x += v0.x; acc0.y += v0.y;
      j += 2;
    }
    if (j < m) {
      int s0 = __shfl(eid, j);
      if (h == 0) {
        float2 v0 = *reinterpret_cast<const float2*>(&Xb[(size_t)s0 * NC + c2 * 2]);
        acc0.x += v0.x; acc0.y += v0.y;
      }
    }
  }
  acc0.x += acc1.x; acc0.y += acc1.y;
  acc0.x += __shfl_xor(acc0.x, 32);
  acc0.y += __shfl_xor(acc0.y, 32);
  if (h == 0) {
    unsigned p0 = (unsigned)f2bf_rne(acc0.x) | ((unsigned)f2bf_rne(acc0.y) << 16);
    *reinterpret_cast<unsigned*>(&H[((size_t)b * N0 + node) * NC + c0 + c2 * 2]) = p0;
  }
}

// ---------- fused GIN MLP: x2 = relu(relu(h0@W1+b1)@W2+b2), fused score ----------
// Swapped mfma operands (D: lane=X-row, regs=4 W-cols -> float4 stores); W in LDS.
__global__ __launch_bounds__(256) void k_gin(const ushort_t* __restrict__ Xh,
                                             float* __restrict__ Xout,
                                             const ushort_t* __restrict__ W1t,
                                             const float* __restrict__ b1,
                                             const ushort_t* __restrict__ W2t,
                                             const float* __restrict__ b2,
                                             const float* __restrict__ pw,
                                             float* __restrict__ score, int n) {
  __shared__ ushort_t Ts[128 * 136];
  __shared__ ushort_t Wsh[128 * 136];
  int b = blockIdx.x & 7;
  int r0 = (blockIdx.x >> 3) * 128;
  int t = threadIdx.x;
  const ushort_t* Xg = Xh + (size_t)b * N0 * NC;

#pragma unroll
  for (int p = 0; p < 8; p++) {
    int id = t + p * 256;
    int row = id >> 4, seg = id & 15;
    short8 vh = (short8)0;
    if (r0 + row < n)
      vh = *reinterpret_cast<const short8*>(&Xg[(size_t)(r0 + row) * NC + seg * 8]);
    *reinterpret_cast<short8*>(&Ts[row * 136 + seg * 8]) = vh;
    *reinterpret_cast<short8*>(&Wsh[row * 136 + seg * 8]) =
        *reinterpret_cast<const short8*>(&W1t[row * NC + seg * 8]);
  }
  __syncthreads();

  int lane = t & 63, w = t >> 6;
  int li = lane & 15, lg = lane >> 4;
  int rbase = w * 32;

  f32x4 acc[2][8];
#pragma unroll
  for (int rt = 0; rt < 2; rt++)
#pragma unroll
    for (int ct = 0; ct < 8; ct++) acc[rt][ct] = (f32x4)0.f;

#pragma unroll
  for (int ks = 0; ks < 4; ks++) {
    short8 x0 = *reinterpret_cast<const short8*>(&Ts[(rbase + li) * 136 + ks * 32 + lg * 8]);
    short8 x1 = *reinterpret_cast<const short8*>(&Ts[(rbase + 16 + li) * 136 + ks * 32 + lg * 8]);
#pragma unroll
    for (int ct = 0; ct < 8; ct++) {
      short8 wf = *reinterpret_cast<const short8*>(&Wsh[(ct * 16 + li) * 136 + ks * 32 + lg * 8]);
      acc[0][ct] = __builtin_amdgcn_mfma_f32_16x16x32_bf16(wf, x0, acc[0][ct], 0, 0, 0);
      acc[1][ct] = __builtin_amdgcn_mfma_f32_16x16x32_bf16(wf, x1, acc[1][ct], 0, 0, 0);
    }
  }

#pragma unroll
  for (int rt = 0; rt < 2; rt++) {
    int row = rbase + rt * 16 + li;
#pragma unroll
    for (int ct = 0; ct < 8; ct++) {
      float4 bq = *reinterpret_cast<const float4*>(&b1[ct * 16 + lg * 4]);
      float o0 = fmaxf(acc[rt][ct][0] + bq.x, 0.f);
      float o1 = fmaxf(acc[rt][ct][1] + bq.y, 0.f);
      float o2 = fmaxf(acc[rt][ct][2] + bq.z, 0.f);
      float o3 = fmaxf(acc[rt][ct][3] + bq.w, 0.f);
      unsigned p0 = (unsigned)f2bf_rne(o0) | ((unsigned)f2bf_rne(o1) << 16);
      unsigned p1 = (unsigned)f2bf_rne(o2) | ((unsigned)f2bf_rne(o3) << 16);
      *reinterpret_cast<uint2*>(&Ts[row * 136 + ct * 16 + lg * 4]) = make_uint2(p0, p1);
    }
  }

  __syncthreads();
#pragma unroll
  for (int p = 0; p < 8; p++) {
    int id = t + p * 256;
    int row = id >> 4, seg = id & 15;
    *reinterpret_cast<short8*>(&Wsh[row * 136 + seg * 8]) =
        *reinterpret_cast<const short8*>(&W2t[row * NC + seg * 8]);
  }
  __syncthreads();

#pragma unroll
  for (int rt = 0; rt < 2; rt++)
#pragma unroll
    for (int ct = 0; ct < 8; ct++) acc[rt][ct] = (f32x4)0.f;

#pragma unroll
  for (int ks = 0; ks < 4; ks++) {
    short8 x0 = *reinterpret_cast<const short8*>(&Ts[(rbase + li) * 136 + ks * 32 + lg * 8]);
    short8 x1 = *reinterpret_cast<const short8*>(&Ts[(rbase + 16 + li) * 136 + ks * 32 + lg * 8]);
#pragma unroll
    for (int ct = 0; ct < 8; ct++) {
      short8 wf = *reinterpret_cast<const short8*>(&Wsh[(ct * 16 + li) * 136 + ks * 32 + lg * 8]);
      acc[0][ct] = __builtin_amdgcn_mfma_f32_16x16x32_bf16(wf, x0, acc[0][ct], 0, 0, 0);
      acc[1][ct] = __builtin_amdgcn_mfma_f32_16x16x32_bf16(wf, x1, acc[1][ct], 0, 0, 0);
    }
  }

  f32x4 pq[8];
  float psum = 0.f;
#pragma unroll
  for (int ct = 0; ct < 8; ct++) {
    pq[ct] = *reinterpret_cast<const f32x4*>(&pw[ct * 16 + lg * 4]);
    psum = fmaf(pq[ct][0], pq[ct][0], psum);
    psum = fmaf(pq[ct][1], pq[ct][1], psum);
    psum = fmaf(pq[ct][2], pq[ct][2], psum);
    psum = fmaf(pq[ct][3], pq[ct][3], psum);
  }
  psum += __shfl_xor(psum, 16);
  psum += __shfl_xor(psum, 32);
  float nrm = sqrtf(psum);

  float* Ob = Xout + (size_t)b * N0 * NC;
#pragma unroll
  for (int rt = 0; rt < 2; rt++) {
    int row = r0 + rbase + rt * 16 + li;
    bool ok = row < n;
    float dot = 0.f;
#pragma unroll
    for (int ct = 0; ct < 8; ct++) {
      float4 bq = *reinterpret_cast<const float4*>(&b2[ct * 16 + lg * 4]);
      float4 o;
      o.x = fmaxf(acc[rt][ct][0] + bq.x, 0.f);
      o.y = fmaxf(acc[rt][ct][1] + bq.y, 0.f);
      o.z = fmaxf(acc[rt][ct][2] + bq.z, 0.f);
      o.w = fmaxf(acc[rt][ct][3] + bq.w, 0.f);
      dot = fmaf(o.x, pq[ct][0], dot);
      dot = fmaf(o.y, pq[ct][1], dot);
      dot = fmaf(o.z, pq[ct][2], dot);
      dot = fmaf(o.w, pq[ct][3], dot);
      if (ok) *reinterpret_cast<float4*>(&Ob[(size_t)row * NC + ct * 16 + lg * 4]) = o;
    }
    dot += __shfl_xor(dot, 16);
    dot += __shfl_xor(dot, 32);
    if (lg == 0 && ok) score[b * N0 + row] = tanhf(dot / nrm);
  }
}

// ---------- top-k threshold via 4-pass radix select (parallel digit scan) ----------
__global__ __launch_bounds__(1024) void k_select(const float* __restrict__ score,
                                                 unsigned* __restrict__ vstar, int* __restrict__ quota,
                                                 int* __restrict__ gcnt, int* __restrict__ tcnt,
                                                 int n, int k) {
  __shared__ int hist[256];
  __shared__ int ss[257];
  __shared__ unsigned s_pref;
  __shared__ int s_r, s_gt;
  int b = blockIdx.x, t = threadIdx.x, lane = t & 63;
  if (t == 0) { s_pref = 0u; s_r = k; s_gt = 0; }
  __syncthreads();
  for (int pass = 0; pass < 4; ++pass) {
    int shift = 24 - pass * 8;
    if (t < 256) hist[t] = 0;
    __syncthreads();
    unsigned pref = s_pref;
    unsigned pmask = (pass == 0) ? 0u : (0xFFFFFFFFu << (shift + 8));
    for (int j0 = 0; j0 < n; j0 += 1024) {
      int j = j0 + t;
      unsigned key = (j < n) ? mono_u(score[b * N0 + j]) : 0u;
      unsigned d = (key >> shift) & 255;
      int contrib = (j < n) && ((key & pmask) == pref);
      unsigned long long bal = __ballot(contrib);
      if (bal == 0) continue;
      int fl = __ffsll((long long)bal) - 1;
      unsigned dref = __shfl(d, fl);
      if (__all(!contrib || d == dref)) {
        if (lane == fl) atomicAdd(&hist[dref], (int)__popcll(bal));
      } else if (contrib) {
        atomicAdd(&hist[d], 1);
      }
    }
    __syncthreads();
    // parallel suffix-sum over 256 bins (Hillis-Steele, 8 steps)
    if (t < 256) ss[t] = hist[t];
    __syncthreads();
    for (int o = 1; o < 256; o <<= 1) {
      int v = 0;
      if (t < 256) v = (t + o < 256) ? ss[t + o] : 0;
      __syncthreads();
      if (t < 256) ss[t] += v;
      __syncthreads();
    }
    int r = s_r;
    __syncthreads();
    if (t < 256) {
      int nxt = (t == 255) ? 0 : ss[t + 1];
      if (ss[t] >= r && nxt < r) {   // unique digit: largest d with suffix >= r
        s_gt += nxt;
        s_r = r - nxt;
        s_pref = pref | ((unsigned)t << shift);
      }
    }
    __syncthreads();
  }
  if (t == 0) {
    vstar[b] = s_pref;
    quota[b] = k - s_gt;
  }
  __syncthreads();
  // fused per-chunk gt/tie counts (wave w owns chunk w)
  unsigned vs = s_pref;
  int w = t >> 6;
  int g = 0, tt = 0;
  for (int it = 0; it < 16; ++it) {
    int j = w * 1024 + it * 64 + lane;
    unsigned key = (j < n) ? mono_u(score[b * N0 + j]) : 0u;
    g += (int)__popcll(__ballot((j < n) && (key > vs)));
    tt += (int)__popcll(__ballot((j < n) && (key == vs)));
  }
  if (lane == 0) { gcnt[b * 16 + w] = g; tcnt[b * 16 + w] = tt; }
}

// ---------- map: assign new ids, jax.lax.top_k tie semantics ----------
__global__ __launch_bounds__(1024) void k_map_wr(const float* __restrict__ score,
                                                 const unsigned* __restrict__ vstar,
                                                 const int* __restrict__ quota,
                                                 const int* __restrict__ gcnt, const int* __restrict__ tcnt,
                                                 int* __restrict__ mp, int n) {
  __shared__ int wg[16], wt[16];
  __shared__ int s_gb, s_tb;
  int b = blockIdx.y, chunk = blockIdx.x, t = threadIdx.x;
  int lane = t & 63, wid = t >> 6;
  if (t == 0) {
    int gb = 0, tb = 0;
    for (int c = 0; c < chunk; c++) { gb += gcnt[b * 16 + c]; tb += tcnt[b * 16 + c]; }
    s_gb = gb; s_tb = tb;
  }
  int j = chunk * 1024 + t;
  unsigned vs = vstar[b];
  int q = quota[b];
  unsigned key = (j < n) ? mono_u(score[b * N0 + j]) : 0u;
  int gt = (j < n) && (key > vs);
  int tie = (j < n) && (key == vs);
  unsigned long long bg = __ballot(gt), bt = __ballot(tie);
  if (lane == 0) { wg[wid] = (int)__popcll(bg); wt[wid] = (int)__popcll(bt); }
  __syncthreads();
  if (j >= n) return;
  unsigned long long ltm = (lane == 63) ? ~0ull >> 1 : ((1ull << lane) - 1);
  int gloc = (int)__popcll(bg & ltm);
  int tloc = (int)__popcll(bt & ltm);
  for (int w = 0; w < 16; w++) {
    if (w < wid) { gloc += wg[w]; tloc += wt[w]; }
  }
  int tie_rank = s_tb + tloc;
  int sel = gt || (tie && tie_rank < q);
  int pos = s_gb + gloc + min(tie_rank, q);
  mp[b * N0 + j] = sel ? pos : -1;
}

// ---------- compact (fused readout, XCD-pinned): Xa[m] = x2[node]*val (f32) ----------
__global__ __launch_bounds__(256) void k_compact(const float* __restrict__ Xin,
                                                 float* __restrict__ Xout,
                                                 const int* __restrict__ mp,
                                                 const float* __restrict__ score,
                                                 int* __restrict__ maxbuf, float* __restrict__ sumbuf,
                                                 int n) {
  __shared__ float smx[128], ssm[128];
  int b = blockIdx.x & 7;
  int base = (blockIdx.x >> 3) * 64;
  if (base >= n) return;
  int c = threadIdx.x & 127, h = threadIdx.x >> 7;
  float mx = -INFINITY, sm = 0.f;
  for (int r = h; r < 64; r += 2) {
    int node = base + r;
    if (node >= n) break;
    int m = mp[b * N0 + node];
    if (m < 0) continue;
    float val = score[b * N0 + node];
    float v = Xin[((size_t)b * N0 + node) * NC + c] * val;
    Xout[((size_t)b * N0 + m) * NC + c] = v;
    mx = fmaxf(mx, v);
    sm += v;
  }
  if (h) { smx[c] = mx; ssm[c] = sm; }
  __syncthreads();
  if (!h) {
    mx = fmaxf(mx, smx[c]);
    sm += ssm[c];
    atomicMax(&maxbuf[b * NC + c], f2ikey(mx));
    atomicAdd(&sumbuf[b * NC + c], sm);
  }
}

// ---------- remap edges in place; count next-depth in-degrees ----------
__global__ void k_remap(int* __restrict__ srcw, int* __restrict__ dstw,
                        const int* __restrict__ mp, int* __restrict__ cnt) {
  int tot = NB * NE;
  int tid = blockIdx.x * blockDim.x + threadIdx.x;
  int stride = gridDim.x * blockDim.x;
  for (int i = tid; i < tot; i += stride) {
    int d = dstw[i];
    if (d < 0) continue;
    int b = i / NE;
    int s = srcw[i];
    int ns = mp[b * N0 + s], nd = mp[b * N0 + d];
    if (ns >= 0 && nd >= 0) {
      srcw[i] = ns;
      dstw[i] = nd;
      atomicAdd(&cnt[b * N0 + nd], 1);
    } else {
      srcw[i] = 0;
      dstw[i] = -1;
    }
  }
}

// ---------- predictor MLP (folds readout-sum across depths) ----------
__global__ __launch_bounds__(256) void k_pred(const int* __restrict__ maxbuf,
                                              const float* __restrict__ sumbuf,
                                              const float* __restrict__ q1w, const float* __restrict__ q1b,
                                              const float* __restrict__ q2w, const float* __restrict__ q2b,
                                              const float* __restrict__ q3w, const float* __restrict__ q3b,
                                              float* __restrict__ out) {
  __shared__ float rr[256], h1[128], h2[64];
  int b = blockIdx.x, t = threadIdx.x;
  const float kdiv[4] = {13108.f, 10487.f, 8390.f, 6712.f};
  float acc = 0.f;
#pragma unroll
  for (int d = 0; d < 4; d++) {
    if (t < 128) acc += ikey2f(maxbuf[d * NB * NC + b * NC + t]);
    else acc += sumbuf[d * NB * NC + b * NC + (t - 128)] / kdiv[d];
  }
  rr[t] = acc;
  __syncthreads();
  if (t < 128) {
    float s = q1b[t];
    for (int j = 0; j < 256; j++) s = fmaf(rr[j], q1w[j * 128 + t], s);
    h1[t] = fmaxf(s, 0.f);
  }
  __syncthreads();
  if (t < 64) {
    float s = q2b[t];
    for (int j = 0; j < 128; j++) s = fmaf(h1[j], q2w[j * 64 + t], s);
    h2[t] = fmaxf(s, 0.f);
  }
  __syncthreads();
  if (t < 2) {
    float s = q3b[t];
    for (int j = 0; j < 64; j++) s = fmaf(h2[j], q3w[j * 2 + t], s);
    out[b * 2 + t] = s;
  }
}

// ---------- host orchestration ----------
extern "C" void kernel_launch(void* const* d_in, const int* in_sizes, int n_in,
                              void* d_out, int out_size, void* d_ws, size_t ws_size,
                              hipStream_t stream) {
  const float* x = (const float*)d_in[0];
  const int* src = (const int*)d_in[1];
  const int* dst = (const int*)d_in[2];
  const float* q1w = (const float*)d_in[23];
  const float* q1b = (const float*)d_in[24];
  const float* q2w = (const float*)d_in[25];
  const float* q2b = (const float*)d_in[26];
  const float* q3w = (const float*)d_in[27];
  const float* q3b = (const float*)d_in[28];

  char* p = (char*)d_ws;
  auto alloc = [&](size_t bytes) {
    char* q = p;
    p += (bytes + 255) & ~(size_t)255;
    return q;
  };
  float* Xa = (float*)alloc((size_t)NB * N0 * NC * 4);       // pooled x (f32)
  float* Xb = (float*)alloc((size_t)NB * N0 * NC * 4);       // x2 (f32, gin out)
  ushort_t* Xh = (ushort_t*)alloc((size_t)NB * N0 * NC * 2); // h0 (bf16)
  int* srcw = (int*)alloc((size_t)NB * NE * 4);
  int* dstw = (int*)alloc((size_t)NB * NE * 4);
  int* elist = (int*)alloc((size_t)NB * NE * 4);
  int* cnt = (int*)alloc((size_t)NB * N0 * 4);
  int* offs = (int*)alloc((size_t)NB * N0 * 4);
  int* cursor = (int*)alloc((size_t)NB * N0 * 4);
  float* score = (float*)alloc((size_t)NB * N0 * 4);
  int* mp = (int*)alloc((size_t)NB * N0 * 4);
  unsigned* vstar = (unsigned*)alloc(256);
  int* quota = (int*)alloc(256);
  int* gcnt = (int*)alloc(NB * 16 * 4);
  int* tcnt = (int*)alloc(NB * 16 * 4);
  int* maxbuf = (int*)alloc(4 * NB * NC * 4);
  float* sumbuf = (float*)alloc(4 * NB * NC * 4);
  ushort_t* Wt_all = (ushort_t*)alloc((size_t)8 * NC * NC * 2);

  hipMemsetAsync(cnt, 0, (size_t)NB * N0 * 4, stream);
  k_init<<<2048, 256, 0, stream>>>(src, dst, srcw, dstw, cnt, maxbuf, sumbuf);
  for (int i = 0; i < 4; i++) {
    k_wprep<<<64, 256, 0, stream>>>((const float*)d_in[3 + i * 5 + 0], Wt_all + (size_t)(2 * i) * NC * NC);
    k_wprep<<<64, 256, 0, stream>>>((const float*)d_in[3 + i * 5 + 2], Wt_all + (size_t)(2 * i + 1) * NC * NC);
  }

  static const int NSv[4] = {16384, 13108, 10487, 8390};
  static const int KSv[4] = {13108, 10487, 8390, 6712};
  for (int i = 0; i < 4; i++) {
    int n = NSv[i], k = KSv[i];
    const float* b1 = (const float*)d_in[3 + i * 5 + 1];
    const float* b2 = (const float*)d_in[3 + i * 5 + 3];
    const float* pw = (const float*)d_in[3 + i * 5 + 4];
    const ushort_t* w1t = Wt_all + (size_t)(2 * i) * NC * NC;
    const ushort_t* w2t = Wt_all + (size_t)(2 * i + 1) * NC * NC;
    const float* cur = (i == 0) ? x : Xa;

    k_scan<<<NB, 1024, 0, stream>>>(cnt, offs, cursor);
    k_fill<<<1024, 256, 0, stream>>>(srcw, dstw, cursor, elist);

    // channel-split gather, round-9-identical summation order per channel;
    // sequential passes keep one 4.2 MB/graph half-row set hot in each XCD L2
    k_gather_h<<<((n + 3) / 4) * 8, 256, 0, stream>>>(cur, Xh, offs, cursor, elist, n, 0);
    k_gather_h<<<((n + 3) / 4) * 8, 256, 0, stream>>>(cur, Xh, offs, cursor, elist, n, 64);

    k_gin<<<((n + 127) / 128) * 8, 256, 0, stream>>>(Xh, Xb, w1t, b1, w2t, b2, pw, score, n);

    k_select<<<NB, 1024, 0, stream>>>(score, vstar, quota, gcnt, tcnt, n, k);
    dim3 gm(16, NB);
    k_map_wr<<<gm, 1024, 0, stream>>>(score, vstar, quota, gcnt, tcnt, mp, n);

    k_compact<<<((n + 63) / 64) * 8, 256, 0, stream>>>(Xb, Xa, mp, score,
                                                       maxbuf + i * NB * NC, sumbuf + i * NB * NC, n);
    k_remap<<<1024, 256, 0, stream>>>(srcw, dstw, mp, cnt);
  }

  k_pred<<<NB, 256, 0, stream>>>(maxbuf, sumbuf, q1w, q1b, q2w, q2b, q3w, q3b, (float*)d_out);
}

// Round 12
// 736.770 us; speedup vs baseline: 1.1167x; 1.1167x over previous
//
#include <hip/hip_runtime.h>
#include <math.h>

#define NB 8
#define N0 16384
#define NC 128
#define NE 98304

typedef unsigned short ushort_t;
using short8 = __attribute__((ext_vector_type(8))) short;
using f32x4 = __attribute__((ext_vector_type(4))) float;

// ---------- helpers ----------
__device__ __forceinline__ unsigned mono_u(float f) {
  unsigned u = __float_as_uint(f);
  return (u & 0x80000000u) ? ~u : (u | 0x80000000u);
}
__device__ __forceinline__ int f2ikey(float f) {
  int i = __float_as_int(f);
  return (i >= 0) ? i : (i ^ 0x7fffffff);
}
__device__ __forceinline__ float ikey2f(int k) {
  return __int_as_float(k >= 0 ? k : (k ^ 0x7fffffff));
}
__device__ __forceinline__ ushort_t f2bf_rne(float f) {
  unsigned u = __float_as_uint(f);
  unsigned r = u + 0x7fffu + ((u >> 16) & 1u);
  return (ushort_t)(r >> 16);
}
__device__ __forceinline__ int wscan_incl(int v, int lane) {
#pragma unroll
  for (int o = 1; o < 64; o <<= 1) {
    int u = __shfl_up(v, o);
    if (lane >= o) v += u;
  }
  return v;
}

// ---------- init: edges copy + depth-0 degree count, readout bufs ----------
// cnt must be pre-zeroed.
__global__ void k_init(const int* __restrict__ src, const int* __restrict__ dst,
                       int* __restrict__ srcw, int* __restrict__ dstw,
                       int* __restrict__ cnt, int* __restrict__ maxbuf, float* __restrict__ sumbuf) {
  int stride = gridDim.x * blockDim.x;
  int i = blockIdx.x * blockDim.x + threadIdx.x;
  for (int j = i; j < NB * NE; j += stride) {
    int d = dst[j];
    srcw[j] = src[j];
    dstw[j] = d;
    atomicAdd(&cnt[(j / NE) * N0 + d], 1);
  }
  for (int j = i; j < 4 * NB * NC; j += stride) {
    maxbuf[j] = (int)0x80000000;
    sumbuf[j] = 0.f;
  }
}

// ---------- weight prep: W[k][c] f32 -> Wt[c][k] bf16 ----------
__global__ void k_wprep(const float* __restrict__ W, ushort_t* __restrict__ Wt) {
  int id = blockIdx.x * blockDim.x + threadIdx.x;
  if (id >= NC * NC) return;
  int k = id >> 7, c = id & 127;
  Wt[c * NC + k] = f2bf_rne(W[id]);
}

// ---------- CSR build: per-graph exclusive scan (wave-shuffle); zeroes cnt ----------
__global__ __launch_bounds__(1024) void k_scan(int* __restrict__ cnt,
                                               int* __restrict__ offs, int* __restrict__ cursor) {
  __shared__ int wsum[16];
  int b = blockIdx.x, t = threadIdx.x, lane = t & 63, wid = t >> 6;
  int base = b * N0 + t * 16;
  int loc[16];
  int s = 0;
#pragma unroll
  for (int j = 0; j < 16; j++) { loc[j] = cnt[base + j]; s += loc[j]; cnt[base + j] = 0; }
  int incl = wscan_incl(s, lane);
  if (lane == 63) wsum[wid] = incl;
  __syncthreads();
  int woff = 0;
  for (int w = 0; w < wid; w++) woff += wsum[w];
  int excl = woff + incl - s;
#pragma unroll
  for (int j = 0; j < 16; j++) {
    offs[base + j] = excl;
    cursor[base + j] = excl;
    excl += loc[j];
  }
}

// ---------- CSR build: fill edge list; cursor ends as end-offset ----------
// NOTE: atomic placement order determines elist order -> summation order.
// Do NOT change this kernel's launch shape (numerics-sensitive downstream).
__global__ void k_fill(const int* __restrict__ srcw, const int* __restrict__ dstw,
                       int* __restrict__ cursor, int* __restrict__ elist) {
  int tot = NB * NE;
  for (int i = blockIdx.x * blockDim.x + threadIdx.x; i < tot; i += gridDim.x * blockDim.x) {
    int d = dstw[i];
    if (d < 0) continue;
    int b = i / NE;
    int pos = atomicAdd(&cursor[b * N0 + d], 1);
    elist[b * NE + pos] = srcw[i];
  }
}

// ---------- gather (f32 in, bf16 out): H[node] = bf16( X[node] + sum_{src} X[src] ) ----------
// 1D grid, graph = blockIdx.x & 7 (XCD-pinned). Half-waves, 2 edges per wave-load.
// Round-9 verbatim: summation order is numerics-sensitive, do not restructure.
__global__ void k_gather(const float* __restrict__ X, ushort_t* __restrict__ H,
                         const int* __restrict__ offs, const int* __restrict__ cend,
                         const int* __restrict__ elist, int n) {
  int b = blockIdx.x & 7;
  int chunk = blockIdx.x >> 3;
  int lane = threadIdx.x & 63, wid = threadIdx.x >> 6;
  int node = chunk * 4 + wid;
  if (node >= n) return;
  int off = offs[b * N0 + node];
  int deg = cend[b * N0 + node] - off;
  int h = lane >> 5, c4 = lane & 31;
  const float* Xb = X + (size_t)b * N0 * NC;

  float4 acc0 = make_float4(0.f, 0.f, 0.f, 0.f);
  float4 acc1 = make_float4(0.f, 0.f, 0.f, 0.f);
  if (h == 0) acc0 = *reinterpret_cast<const float4*>(&Xb[(size_t)node * NC + c4 * 4]);

  for (int base = 0; base < deg; base += 64) {
    int m = min(64, deg - base);
    int eid = (lane < m) ? elist[b * NE + off + base + lane] : 0;
    int j = 0;
    for (; j + 4 <= m; j += 4) {
      int s0 = __shfl(eid, j + h);
      int s1 = __shfl(eid, j + 2 + h);
      float4 v0 = *reinterpret_cast<const float4*>(&Xb[(size_t)s0 * NC + c4 * 4]);
      float4 v1 = *reinterpret_cast<const float4*>(&Xb[(size_t)s1 * NC + c4 * 4]);
      acc0.x += v0.x; acc0.y += v0.y; acc0.z += v0.z; acc0.w += v0.w;
      acc1.x += v1.x; acc1.y += v1.y; acc1.z += v1.z; acc1.w += v1.w;
    }
    if (j + 2 <= m) {
      int s0 = __shfl(eid, j + h);
      float4 v0 = *reinterpret_cast<const float4*>(&Xb[(size_t)s0 * NC + c4 * 4]);
      acc0.x += v0.x; acc0.y += v0.y; acc0.z += v0.z; acc0.w += v0.w;
      j += 2;
    }
    if (j < m) {
      int s0 = __shfl(eid, j);
      if (h == 0) {
        float4 v0 = *reinterpret_cast<const float4*>(&Xb[(size_t)s0 * NC + c4 * 4]);
        acc0.x += v0.x; acc0.y += v0.y; acc0.z += v0.z; acc0.w += v0.w;
      }
    }
  }
  acc0.x += acc1.x; acc0.y += acc1.y; acc0.z += acc1.z; acc0.w += acc1.w;
  acc0.x += __shfl_xor(acc0.x, 32);
  acc0.y += __shfl_xor(acc0.y, 32);
  acc0.z += __shfl_xor(acc0.z, 32);
  acc0.w += __shfl_xor(acc0.w, 32);
  if (h == 0) {
    unsigned p0 = (unsigned)f2bf_rne(acc0.x) | ((unsigned)f2bf_rne(acc0.y) << 16);
    unsigned p1 = (unsigned)f2bf_rne(acc0.z) | ((unsigned)f2bf_rne(acc0.w) << 16);
    *reinterpret_cast<uint2*>(&H[((size_t)b * N0 + node) * NC + c4 * 4]) = make_uint2(p0, p1);
  }
}

// ---------- fused GIN MLP: x2 = relu(relu(h0@W1+b1)@W2+b2), fused score ----------
// Swapped mfma operands (D: lane=X-row, regs=4 W-cols -> float4 stores); W in LDS.
__global__ __launch_bounds__(256) void k_gin(const ushort_t* __restrict__ Xh,
                                             float* __restrict__ Xout,
                                             const ushort_t* __restrict__ W1t,
                                             const float* __restrict__ b1,
                                             const ushort_t* __restrict__ W2t,
                                             const float* __restrict__ b2,
                                             const float* __restrict__ pw,
                                             float* __restrict__ score, int n) {
  __shared__ ushort_t Ts[128 * 136];
  __shared__ ushort_t Wsh[128 * 136];
  int b = blockIdx.x & 7;
  int r0 = (blockIdx.x >> 3) * 128;
  int t = threadIdx.x;
  const ushort_t* Xg = Xh + (size_t)b * N0 * NC;

#pragma unroll
  for (int p = 0; p < 8; p++) {
    int id = t + p * 256;
    int row = id >> 4, seg = id & 15;
    short8 vh = (short8)0;
    if (r0 + row < n)
      vh = *reinterpret_cast<const short8*>(&Xg[(size_t)(r0 + row) * NC + seg * 8]);
    *reinterpret_cast<short8*>(&Ts[row * 136 + seg * 8]) = vh;
    *reinterpret_cast<short8*>(&Wsh[row * 136 + seg * 8]) =
        *reinterpret_cast<const short8*>(&W1t[row * NC + seg * 8]);
  }
  __syncthreads();

  int lane = t & 63, w = t >> 6;
  int li = lane & 15, lg = lane >> 4;
  int rbase = w * 32;

  f32x4 acc[2][8];
#pragma unroll
  for (int rt = 0; rt < 2; rt++)
#pragma unroll
    for (int ct = 0; ct < 8; ct++) acc[rt][ct] = (f32x4)0.f;

#pragma unroll
  for (int ks = 0; ks < 4; ks++) {
    short8 x0 = *reinterpret_cast<const short8*>(&Ts[(rbase + li) * 136 + ks * 32 + lg * 8]);
    short8 x1 = *reinterpret_cast<const short8*>(&Ts[(rbase + 16 + li) * 136 + ks * 32 + lg * 8]);
#pragma unroll
    for (int ct = 0; ct < 8; ct++) {
      short8 wf = *reinterpret_cast<const short8*>(&Wsh[(ct * 16 + li) * 136 + ks * 32 + lg * 8]);
      acc[0][ct] = __builtin_amdgcn_mfma_f32_16x16x32_bf16(wf, x0, acc[0][ct], 0, 0, 0);
      acc[1][ct] = __builtin_amdgcn_mfma_f32_16x16x32_bf16(wf, x1, acc[1][ct], 0, 0, 0);
    }
  }

#pragma unroll
  for (int rt = 0; rt < 2; rt++) {
    int row = rbase + rt * 16 + li;
#pragma unroll
    for (int ct = 0; ct < 8; ct++) {
      float4 bq = *reinterpret_cast<const float4*>(&b1[ct * 16 + lg * 4]);
      float o0 = fmaxf(acc[rt][ct][0] + bq.x, 0.f);
      float o1 = fmaxf(acc[rt][ct][1] + bq.y, 0.f);
      float o2 = fmaxf(acc[rt][ct][2] + bq.z, 0.f);
      float o3 = fmaxf(acc[rt][ct][3] + bq.w, 0.f);
      unsigned p0 = (unsigned)f2bf_rne(o0) | ((unsigned)f2bf_rne(o1) << 16);
      unsigned p1 = (unsigned)f2bf_rne(o2) | ((unsigned)f2bf_rne(o3) << 16);
      *reinterpret_cast<uint2*>(&Ts[row * 136 + ct * 16 + lg * 4]) = make_uint2(p0, p1);
    }
  }

  __syncthreads();
#pragma unroll
  for (int p = 0; p < 8; p++) {
    int id = t + p * 256;
    int row = id >> 4, seg = id & 15;
    *reinterpret_cast<short8*>(&Wsh[row * 136 + seg * 8]) =
        *reinterpret_cast<const short8*>(&W2t[row * NC + seg * 8]);
  }
  __syncthreads();

#pragma unroll
  for (int rt = 0; rt < 2; rt++)
#pragma unroll
    for (int ct = 0; ct < 8; ct++) acc[rt][ct] = (f32x4)0.f;

#pragma unroll
  for (int ks = 0; ks < 4; ks++) {
    short8 x0 = *reinterpret_cast<const short8*>(&Ts[(rbase + li) * 136 + ks * 32 + lg * 8]);
    short8 x1 = *reinterpret_cast<const short8*>(&Ts[(rbase + 16 + li) * 136 + ks * 32 + lg * 8]);
#pragma unroll
    for (int ct = 0; ct < 8; ct++) {
      short8 wf = *reinterpret_cast<const short8*>(&Wsh[(ct * 16 + li) * 136 + ks * 32 + lg * 8]);
      acc[0][ct] = __builtin_amdgcn_mfma_f32_16x16x32_bf16(wf, x0, acc[0][ct], 0, 0, 0);
      acc[1][ct] = __builtin_amdgcn_mfma_f32_16x16x32_bf16(wf, x1, acc[1][ct], 0, 0, 0);
    }
  }

  f32x4 pq[8];
  float psum = 0.f;
#pragma unroll
  for (int ct = 0; ct < 8; ct++) {
    pq[ct] = *reinterpret_cast<const f32x4*>(&pw[ct * 16 + lg * 4]);
    psum = fmaf(pq[ct][0], pq[ct][0], psum);
    psum = fmaf(pq[ct][1], pq[ct][1], psum);
    psum = fmaf(pq[ct][2], pq[ct][2], psum);
    psum = fmaf(pq[ct][3], pq[ct][3], psum);
  }
  psum += __shfl_xor(psum, 16);
  psum += __shfl_xor(psum, 32);
  float nrm = sqrtf(psum);

  float* Ob = Xout + (size_t)b * N0 * NC;
#pragma unroll
  for (int rt = 0; rt < 2; rt++) {
    int row = r0 + rbase + rt * 16 + li;
    bool ok = row < n;
    float dot = 0.f;
#pragma unroll
    for (int ct = 0; ct < 8; ct++) {
      float4 bq = *reinterpret_cast<const float4*>(&b2[ct * 16 + lg * 4]);
      float4 o;
      o.x = fmaxf(acc[rt][ct][0] + bq.x, 0.f);
      o.y = fmaxf(acc[rt][ct][1] + bq.y, 0.f);
      o.z = fmaxf(acc[rt][ct][2] + bq.z, 0.f);
      o.w = fmaxf(acc[rt][ct][3] + bq.w, 0.f);
      dot = fmaf(o.x, pq[ct][0], dot);
      dot = fmaf(o.y, pq[ct][1], dot);
      dot = fmaf(o.z, pq[ct][2], dot);
      dot = fmaf(o.w, pq[ct][3], dot);
      if (ok) *reinterpret_cast<float4*>(&Ob[(size_t)row * NC + ct * 16 + lg * 4]) = o;
    }
    dot += __shfl_xor(dot, 16);
    dot += __shfl_xor(dot, 32);
    if (lg == 0 && ok) score[b * N0 + row] = tanhf(dot / nrm);
  }
}

// ---------- top-k threshold via 4-pass radix select (parallel digit scan) ----------
__global__ __launch_bounds__(1024) void k_select(const float* __restrict__ score,
                                                 unsigned* __restrict__ vstar, int* __restrict__ quota,
                                                 int* __restrict__ gcnt, int* __restrict__ tcnt,
                                                 int n, int k) {
  __shared__ int hist[256];
  __shared__ int ss[257];
  __shared__ unsigned s_pref;
  __shared__ int s_r, s_gt;
  int b = blockIdx.x, t = threadIdx.x, lane = t & 63;
  if (t == 0) { s_pref = 0u; s_r = k; s_gt = 0; }
  __syncthreads();
  for (int pass = 0; pass < 4; ++pass) {
    int shift = 24 - pass * 8;
    if (t < 256) hist[t] = 0;
    __syncthreads();
    unsigned pref = s_pref;
    unsigned pmask = (pass == 0) ? 0u : (0xFFFFFFFFu << (shift + 8));
    for (int j0 = 0; j0 < n; j0 += 1024) {
      int j = j0 + t;
      unsigned key = (j < n) ? mono_u(score[b * N0 + j]) : 0u;
      unsigned d = (key >> shift) & 255;
      int contrib = (j < n) && ((key & pmask) == pref);
      unsigned long long bal = __ballot(contrib);
      if (bal == 0) continue;
      int fl = __ffsll((long long)bal) - 1;
      unsigned dref = __shfl(d, fl);
      if (__all(!contrib || d == dref)) {
        if (lane == fl) atomicAdd(&hist[dref], (int)__popcll(bal));
      } else if (contrib) {
        atomicAdd(&hist[d], 1);
      }
    }
    __syncthreads();
    // parallel suffix-sum over 256 bins (Hillis-Steele, 8 steps)
    if (t < 256) ss[t] = hist[t];
    __syncthreads();
    for (int o = 1; o < 256; o <<= 1) {
      int v = 0;
      if (t < 256) v = (t + o < 256) ? ss[t + o] : 0;
      __syncthreads();
      if (t < 256) ss[t] += v;
      __syncthreads();
    }
    int r = s_r;
    __syncthreads();
    if (t < 256) {
      int nxt = (t == 255) ? 0 : ss[t + 1];
      if (ss[t] >= r && nxt < r) {   // unique digit: largest d with suffix >= r
        s_gt += nxt;
        s_r = r - nxt;
        s_pref = pref | ((unsigned)t << shift);
      }
    }
    __syncthreads();
  }
  if (t == 0) {
    vstar[b] = s_pref;
    quota[b] = k - s_gt;
  }
  __syncthreads();
  // fused per-chunk gt/tie counts (wave w owns chunk w)
  unsigned vs = s_pref;
  int w = t >> 6;
  int g = 0, tt = 0;
  for (int it = 0; it < 16; ++it) {
    int j = w * 1024 + it * 64 + lane;
    unsigned key = (j < n) ? mono_u(score[b * N0 + j]) : 0u;
    g += (int)__popcll(__ballot((j < n) && (key > vs)));
    tt += (int)__popcll(__ballot((j < n) && (key == vs)));
  }
  if (lane == 0) { gcnt[b * 16 + w] = g; tcnt[b * 16 + w] = tt; }
}

// ---------- map: assign new ids, jax.lax.top_k tie semantics ----------
__global__ __launch_bounds__(1024) void k_map_wr(const float* __restrict__ score,
                                                 const unsigned* __restrict__ vstar,
                                                 const int* __restrict__ quota,
                                                 const int* __restrict__ gcnt, const int* __restrict__ tcnt,
                                                 int* __restrict__ mp, int n) {
  __shared__ int wg[16], wt[16];
  __shared__ int s_gb, s_tb;
  int b = blockIdx.y, chunk = blockIdx.x, t = threadIdx.x;
  int lane = t & 63, wid = t >> 6;
  if (t == 0) {
    int gb = 0, tb = 0;
    for (int c = 0; c < chunk; c++) { gb += gcnt[b * 16 + c]; tb += tcnt[b * 16 + c]; }
    s_gb = gb; s_tb = tb;
  }
  int j = chunk * 1024 + t;
  unsigned vs = vstar[b];
  int q = quota[b];
  unsigned key = (j < n) ? mono_u(score[b * N0 + j]) : 0u;
  int gt = (j < n) && (key > vs);
  int tie = (j < n) && (key == vs);
  unsigned long long bg = __ballot(gt), bt = __ballot(tie);
  if (lane == 0) { wg[wid] = (int)__popcll(bg); wt[wid] = (int)__popcll(bt); }
  __syncthreads();
  if (j >= n) return;
  unsigned long long ltm = (lane == 63) ? ~0ull >> 1 : ((1ull << lane) - 1);
  int gloc = (int)__popcll(bg & ltm);
  int tloc = (int)__popcll(bt & ltm);
  for (int w = 0; w < 16; w++) {
    if (w < wid) { gloc += wg[w]; tloc += wt[w]; }
  }
  int tie_rank = s_tb + tloc;
  int sel = gt || (tie && tie_rank < q);
  int pos = s_gb + gloc + min(tie_rank, q);
  mp[b * N0 + j] = sel ? pos : -1;
}

// ---------- compact (fused readout, XCD-pinned): Xa[m] = x2[node]*val (f32) ----------
__global__ __launch_bounds__(256) void k_compact(const float* __restrict__ Xin,
                                                 float* __restrict__ Xout,
                                                 const int* __restrict__ mp,
                                                 const float* __restrict__ score,
                                                 int* __restrict__ maxbuf, float* __restrict__ sumbuf,
                                                 int n) {
  __shared__ float smx[128], ssm[128];
  int b = blockIdx.x & 7;
  int base = (blockIdx.x >> 3) * 64;
  if (base >= n) return;
  int c = threadIdx.x & 127, h = threadIdx.x >> 7;
  float mx = -INFINITY, sm = 0.f;
  for (int r = h; r < 64; r += 2) {
    int node = base + r;
    if (node >= n) break;
    int m = mp[b * N0 + node];
    if (m < 0) continue;
    float val = score[b * N0 + node];
    float v = Xin[((size_t)b * N0 + node) * NC + c] * val;
    Xout[((size_t)b * N0 + m) * NC + c] = v;
    mx = fmaxf(mx, v);
    sm += v;
  }
  if (h) { smx[c] = mx; ssm[c] = sm; }
  __syncthreads();
  if (!h) {
    mx = fmaxf(mx, smx[c]);
    sm += ssm[c];
    atomicMax(&maxbuf[b * NC + c], f2ikey(mx));
    atomicAdd(&sumbuf[b * NC + c], sm);
  }
}

// ---------- remap edges in place (XCD-pinned per graph); count next-depth degrees ----------
__global__ void k_remap(int* __restrict__ srcw, int* __restrict__ dstw,
                        const int* __restrict__ mp, int* __restrict__ cnt) {
  int b = blockIdx.x & 7;
  int bi = blockIdx.x >> 3;
  int nblk = gridDim.x >> 3;
  for (int e = bi * blockDim.x + threadIdx.x; e < NE; e += nblk * blockDim.x) {
    int i = b * NE + e;
    int d = dstw[i];
    if (d < 0) continue;
    int s = srcw[i];
    int ns = mp[b * N0 + s], nd = mp[b * N0 + d];
    if (ns >= 0 && nd >= 0) {
      srcw[i] = ns;
      dstw[i] = nd;
      atomicAdd(&cnt[b * N0 + nd], 1);
    } else {
      srcw[i] = 0;
      dstw[i] = -1;
    }
  }
}

// ---------- predictor MLP (folds readout-sum across depths) ----------
__global__ __launch_bounds__(256) void k_pred(const int* __restrict__ maxbuf,
                                              const float* __restrict__ sumbuf,
                                              const float* __restrict__ q1w, const float* __restrict__ q1b,
                                              const float* __restrict__ q2w, const float* __restrict__ q2b,
                                              const float* __restrict__ q3w, const float* __restrict__ q3b,
                                              float* __restrict__ out) {
  __shared__ float rr[256], h1[128], h2[64];
  int b = blockIdx.x, t = threadIdx.x;
  const float kdiv[4] = {13108.f, 10487.f, 8390.f, 6712.f};
  float acc = 0.f;
#pragma unroll
  for (int d = 0; d < 4; d++) {
    if (t < 128) acc += ikey2f(maxbuf[d * NB * NC + b * NC + t]);
    else acc += sumbuf[d * NB * NC + b * NC + (t - 128)] / kdiv[d];
  }
  rr[t] = acc;
  __syncthreads();
  if (t < 128) {
    float s = q1b[t];
    for (int j = 0; j < 256; j++) s = fmaf(rr[j], q1w[j * 128 + t], s);
    h1[t] = fmaxf(s, 0.f);
  }
  __syncthreads();
  if (t < 64) {
    float s = q2b[t];
    for (int j = 0; j < 128; j++) s = fmaf(h1[j], q2w[j * 64 + t], s);
    h2[t] = fmaxf(s, 0.f);
  }
  __syncthreads();
  if (t < 2) {
    float s = q3b[t];
    for (int j = 0; j < 64; j++) s = fmaf(h2[j], q3w[j * 2 + t], s);
    out[b * 2 + t] = s;
  }
}

// ---------- host orchestration ----------
extern "C" void kernel_launch(void* const* d_in, const int* in_sizes, int n_in,
                              void* d_out, int out_size, void* d_ws, size_t ws_size,
                              hipStream_t stream) {
  const float* x = (const float*)d_in[0];
  const int* src = (const int*)d_in[1];
  const int* dst = (const int*)d_in[2];
  const float* q1w = (const float*)d_in[23];
  const float* q1b = (const float*)d_in[24];
  const float* q2w = (const float*)d_in[25];
  const float* q2b = (const float*)d_in[26];
  const float* q3w = (const float*)d_in[27];
  const float* q3b = (const float*)d_in[28];

  char* p = (char*)d_ws;
  auto alloc = [&](size_t bytes) {
    char* q = p;
    p += (bytes + 255) & ~(size_t)255;
    return q;
  };
  float* Xa = (float*)alloc((size_t)NB * N0 * NC * 4);       // pooled x (f32)
  float* Xb = (float*)alloc((size_t)NB * N0 * NC * 4);       // x2 (f32, gin out)
  ushort_t* Xh = (ushort_t*)alloc((size_t)NB * N0 * NC * 2); // h0 (bf16)
  int* srcw = (int*)alloc((size_t)NB * NE * 4);
  int* dstw = (int*)alloc((size_t)NB * NE * 4);
  int* elist = (int*)alloc((size_t)NB * NE * 4);
  int* cnt = (int*)alloc((size_t)NB * N0 * 4);
  int* offs = (int*)alloc((size_t)NB * N0 * 4);
  int* cursor = (int*)alloc((size_t)NB * N0 * 4);
  float* score = (float*)alloc((size_t)NB * N0 * 4);
  int* mp = (int*)alloc((size_t)NB * N0 * 4);
  unsigned* vstar = (unsigned*)alloc(256);
  int* quota = (int*)alloc(256);
  int* gcnt = (int*)alloc(NB * 16 * 4);
  int* tcnt = (int*)alloc(NB * 16 * 4);
  int* maxbuf = (int*)alloc(4 * NB * NC * 4);
  float* sumbuf = (float*)alloc(4 * NB * NC * 4);
  ushort_t* Wt_all = (ushort_t*)alloc((size_t)8 * NC * NC * 2);

  hipMemsetAsync(cnt, 0, (size_t)NB * N0 * 4, stream);
  k_init<<<2048, 256, 0, stream>>>(src, dst, srcw, dstw, cnt, maxbuf, sumbuf);
  for (int i = 0; i < 4; i++) {
    k_wprep<<<64, 256, 0, stream>>>((const float*)d_in[3 + i * 5 + 0], Wt_all + (size_t)(2 * i) * NC * NC);
    k_wprep<<<64, 256, 0, stream>>>((const float*)d_in[3 + i * 5 + 2], Wt_all + (size_t)(2 * i + 1) * NC * NC);
  }

  static const int NSv[4] = {16384, 13108, 10487, 8390};
  static const int KSv[4] = {13108, 10487, 8390, 6712};
  for (int i = 0; i < 4; i++) {
    int n = NSv[i], k = KSv[i];
    const float* b1 = (const float*)d_in[3 + i * 5 + 1];
    const float* b2 = (const float*)d_in[3 + i * 5 + 3];
    const float* pw = (const float*)d_in[3 + i * 5 + 4];
    const ushort_t* w1t = Wt_all + (size_t)(2 * i) * NC * NC;
    const ushort_t* w2t = Wt_all + (size_t)(2 * i + 1) * NC * NC;
    const float* cur = (i == 0) ? x : Xa;

    k_scan<<<NB, 1024, 0, stream>>>(cnt, offs, cursor);
    k_fill<<<1024, 256, 0, stream>>>(srcw, dstw, cursor, elist);

    k_gather<<<((n + 3) / 4) * 8, 256, 0, stream>>>(cur, Xh, offs, cursor, elist, n);

    k_gin<<<((n + 127) / 128) * 8, 256, 0, stream>>>(Xh, Xb, w1t, b1, w2t, b2, pw, score, n);

    k_select<<<NB, 1024, 0, stream>>>(score, vstar, quota, gcnt, tcnt, n, k);
    dim3 gm(16, NB);
    k_map_wr<<<gm, 1024, 0, stream>>>(score, vstar, quota, gcnt, tcnt, mp, n);

    k_compact<<<((n + 63) / 64) * 8, 256, 0, stream>>>(Xb, Xa, mp, score,
                                                       maxbuf + i * NB * NC, sumbuf + i * NB * NC, n);
    k_remap<<<512, 256, 0, stream>>>(srcw, dstw, mp, cnt);
  }

  k_pred<<<NB, 256, 0, stream>>>(maxbuf, sumbuf, q1w, q1b, q2w, q2b, q3w, q3b, (float*)d_out);
}